// Round 6
// baseline (2838.633 us; speedup 1.0000x reference)
//
#include <hip/hip_runtime.h>
#include <hip/hip_bf16.h>
#include <type_traits>

// SLSTM recurrence + Linear.  B=1024, T=2048, IN=16, H=128, OUT=1.
// R17 = R16 + dual-WG-per-CU skew (the de-lockstep round):
//   R16 counters: step 1207 cyc/SIMD = matrix 615 (MfmaUtil 51%, at the
//   128-MFMA/WG/step h-GEMM instruction floor) + ~590 exposed non-matrix
//   (VALU + trans + zf LDS round trip + barrier), ADDITIVE because all
//   8 waves sit behind one WG barrier in lockstep: 2 waves/SIMD stall at
//   the same post-barrier zf-latency + serial-tail bubbles.
//   Fix: 512 WGs x NROWS=2 -> 2 WGs/CU -> 4 waves/SIMD from TWO independent
//   barrier groups.  WG A's bubbles are filled by WG B's MFMAs (natural
//   skew, no code support needed).  Per-step matrix demand per SIMD is
//   unchanged (68 MFMA per double-step); step floor -> max(matrix ~660,
//   VALU ~590) instead of their sum.
//   Minimal delta from verified R16: keep ALL layouts and sizes; N-slots
//   nb>=2 simply stay zero (init zeroes them; MFMA adds 0; junk lanes
//   compute benign finite values and never write).  Guards: h-write
//   (c16&2)==0, staging b_loc<2, epilogue lane<2/tid<2.
//   VGPR must stay <=128 for 4 waves/SIMD: __launch_bounds__(512, 4)
//   (R16 measured 120).
// R15/R16 recap: quad-batched x-projection at N-fill 16 (one x-MFMA per
//   gate per 4 timesteps; 34->17 MFMA/wave/step), rotating reader window
//   with broadcast-zero for out-of-window lanes, pack4p<P> dpp extraction.
// R12/R13/R14 lessons: o-chain in P2 with 1:6 VALU interleave; no chain
//   flattening; cvt_pk h-write; o-gate hoisted off the post-ec serial path.

#define T_LEN 2048
#define IN_DIM 16
#define CHUNK 32
#define NROWS 2

typedef __attribute__((ext_vector_type(4))) float f32x4;
typedef __attribute__((ext_vector_type(8))) short s16x8;

__device__ __forceinline__ short f2bf(float f) {
    union { float f; unsigned u; } v; v.f = f;
    unsigned r = v.u + 0x7fffu + ((v.u >> 16) & 1u);   // RNE
    return (short)(r >> 16);
}
__device__ __forceinline__ unsigned pk_bf16(float a, float b) {
#if __has_builtin(__builtin_amdgcn_cvt_pk_bf16_f32)
    typedef __attribute__((ext_vector_type(2))) __bf16 bf16x2;
    bf16x2 r = __builtin_amdgcn_cvt_pk_bf16_f32(a, b);
    union { bf16x2 v; unsigned u; } c; c.v = r;
    return c.u;
#else
    return (unsigned)(unsigned short)f2bf(a) | ((unsigned)(unsigned short)f2bf(b) << 16);
#endif
}
// Phase-P pack: lane group e (lanes 4e..4e+3 of each 16-row) takes acc reg e
// from source lane 4P+nb via row_ror:4((e-P)&3).  Shift amounts are fixed
// (4,8,12); only the bank masks rotate with P.  P=0 == verified R10 pack4.
template<int P>
__device__ __forceinline__ float pack4p(const f32x4& a) {
    int d = __float_as_int(a[P]);
    d = __builtin_amdgcn_update_dpp(d, __float_as_int(a[(P + 1) & 3]), 0x124, 0xF, 1 << ((P + 1) & 3), false);
    d = __builtin_amdgcn_update_dpp(d, __float_as_int(a[(P + 2) & 3]), 0x128, 0xF, 1 << ((P + 2) & 3), false);
    d = __builtin_amdgcn_update_dpp(d, __float_as_int(a[(P + 3) & 3]), 0x12C, 0xF, 1 << ((P + 3) & 3), false);
    return __int_as_float(d);
}

__global__ __launch_bounds__(512, 4)
void slstm_persistent(const float* __restrict__ x,
                      const float* __restrict__ W_ih,
                      const float* __restrict__ W_hh,
                      const float* __restrict__ b_ih,
                      const float* __restrict__ b_hh,
                      const float* __restrict__ fc_w,
                      const float* __restrict__ fc_b,
                      float* __restrict__ out)
{
    // h: 5 buffers x [kf 4][chunk 16][8 shorts]; element (k=col, nb) at
    // shorts[(k>>5)*128 + ((k>>3)&3)*32 + nb*8 + (k&7)].  Buffer p written at
    // phase p; buffer 4 permanently zero.  nb>=2 slots never written (zero).
    __shared__ __align__(16) unsigned short h_frag[5][512];
    // x quad-frags: [buf 2][quadslot 8][512 shorts]; B[k][c=4s+nb].
    // nb>=2 and k>=16 slots permanently zero.
    __shared__ __align__(16) unsigned short xq[8192];     // 16 KB
    __shared__ float red[NROWS];

    const int tid  = threadIdx.x;
    const int lane = tid & 63;
    const int wv   = tid >> 6;          // wave 0..7 = col-group
    const int c16  = lane & 15;
    const int quad = lane >> 4;         // 0..3
    const int b0   = blockIdx.x * NROWS;

    const float kNL2E = -1.44269504f;

    // ---- weights pre-scaled; wave owns col-group wv x 4 gates ----
    s16x8 wfrag[4][5];                  // [g][kf], kf4 = x (k>=IN_DIM zeroed)
    f32x4 biasC[4];
    #pragma unroll
    for (int g = 0; g < 4; ++g) {
        const float scale = (g == 2) ? (2.0f * kNL2E) : kNL2E;
        const int n = g * 128 + wv * 16 + c16;
        #pragma unroll
        for (int kf = 0; kf < 5; ++kf) {
            s16x8 fr;
            #pragma unroll
            for (int j = 0; j < 8; ++j) {
                const int k = kf * 32 + quad * 8 + j;
                float v;
                if (kf < 4) v = W_hh[n * 128 + k];
                else {
                    const int kk = k - 128;
                    v = (kk < IN_DIM) ? W_ih[n * IN_DIM + kk] : 0.0f;
                }
                fr[j] = f2bf(v * scale);
            }
            wfrag[g][kf] = fr;
        }
        #pragma unroll
        for (int r = 0; r < 4; ++r) {
            const int m = g * 128 + wv * 16 + quad * 4 + r;
            biasC[g][r] = (b_ih[m] + b_hh[m]) * scale;
        }
    }

    // ---- zero h buffers (incl. zero-source buf 4) and xq ----
    {
        unsigned* hz = (unsigned*)h_frag;      // 1280 unsigneds (5120 B)
        hz[tid] = 0; hz[tid + 512] = 0;
        if (tid < 256) hz[tid + 1024] = 0;
        unsigned* xz = (unsigned*)xq;          // 4096 unsigneds (16 KB)
        #pragma unroll
        for (int i = 0; i < 8; ++i) xz[tid + i * 512] = 0;
    }
    __syncthreads();

    // ---- packed-lane identity: element (col, nb) — fixed across phases ----
    const int e    = c16 >> 2;
    const int nb   = c16 & 3;                  // valid rows: nb < 2
    const int col  = wv * 16 + quad * 4 + e;
    const int waddr = (col >> 5) * 128 + ((col >> 3) & 3) * 32 + nb * 8 + (col & 7);
    // per-phase h read offset: window lanes (c16>>2 == p) read buffer (p+3)&3
    // at chunk quad*4 + (c16&3); all other lanes read ONE broadcast address
    // (zero buf 4, offset 0) -> no conflicts (R16 fix).
    int hoffP[4];
    #pragma unroll
    for (int q = 0; q < 4; ++q)
        hoffP[q] = ((c16 >> 2) == q)
                 ? ((q + 3) & 3) * 1024 + (quad * 4 + (c16 & 3)) * 16
                 : 4 * 1024;

    float c_st = 0.0f, h_ep = 0.0f;

    // ---- prologue: stage chunk 0 -> xq buf0 (rows 0,1 only); chunk1 -> xreg ----
    f32x4 xreg = {0.f, 0.f, 0.f, 0.f};
    {
        const int flat4 = tid * 4;
        const int b_loc = flat4 >> 9;          // 0..3; only <2 valid
        const int rem   = flat4 & 511;
        if (b_loc < NROWS) {
            const float* xr = x + (size_t)(b0 + b_loc) * (T_LEN * IN_DIM);
            f32x4 v4 = *(const f32x4*)(xr + rem);
            const int slot = rem >> 4, f = rem & 15;
            const int qs = slot >> 2, s = slot & 3;
            unsigned* dst = (unsigned*)&xq[qs * 512 + (f >> 3) * 128 + (4 * s + b_loc) * 8 + (f & 7)];
            dst[0] = pk_bf16(v4[0], v4[1]);
            dst[1] = pk_bf16(v4[2], v4[3]);
            xreg = *(const f32x4*)(xr + CHUNK * IN_DIM + rem);
        }
    }
    __syncthreads();

    // ---- seed quad 0: zx4 walks 1 KB per quad through the 16 KB xq ----
    const char* xb = (const char*)xq;
    s16x8 zx4r = *(const s16x8*)(xb + lane * 16);           // quad 0
    f32x4 accA[4], accB[4];
    #pragma unroll
    for (int g = 0; g < 4; ++g)
        accA[g] = __builtin_amdgcn_mfma_f32_16x16x32_bf16(wfrag[g][4], zx4r, biasC[g], 0, 0, 0);
    zx4r = *(const s16x8*)(xb + 1024 + lane * 16);          // quad 1
    int xqoff = 2 * 1024 + lane * 16;                       // next prefetch: quad 2

    const char* hb = (const char*)h_frag;
    unsigned short* hw = (unsigned short*)h_frag;

    // one phase = one timestep.  acc: current quad's gates; accn: next quad's
    // seeds (gate P reseeded at phase P).
    auto phaseF = [&](auto Pc, f32x4 (&acc)[4], f32x4 (&accn)[4]) {
        constexpr int P = decltype(Pc)::value;
        s16x8 zf[4];
        #pragma unroll
        for (int kf = 0; kf < 4; ++kf)
            zf[kf] = *(const s16x8*)(hb + hoffP[P] + kf * 256);

        // ---- P1: g,i,f chains interleaved (12 MFMA — pure matrix phase) ----
        #pragma unroll
        for (int kf = 0; kf < 4; ++kf) {
            acc[2] = __builtin_amdgcn_mfma_f32_16x16x32_bf16(wfrag[2][kf], zf[kf], acc[2], 0, 0, 0);
            acc[0] = __builtin_amdgcn_mfma_f32_16x16x32_bf16(wfrag[0][kf], zf[kf], acc[0], 0, 0, 0);
            acc[1] = __builtin_amdgcn_mfma_f32_16x16x32_bf16(wfrag[1][kf], zf[kf], acc[1], 0, 0, 0);
        }
        __builtin_amdgcn_sched_barrier(0);

        // ---- P2: o-chain (4 dep MFMA) || packs+exp2 + c-numerator ----
        acc[3] = __builtin_amdgcn_mfma_f32_16x16x32_bf16(wfrag[3][0], zf[0], acc[3], 0, 0, 0);
        acc[3] = __builtin_amdgcn_mfma_f32_16x16x32_bf16(wfrag[3][1], zf[1], acc[3], 0, 0, 0);
        acc[3] = __builtin_amdgcn_mfma_f32_16x16x32_bf16(wfrag[3][2], zf[2], acc[3], 0, 0, 0);
        acc[3] = __builtin_amdgcn_mfma_f32_16x16x32_bf16(wfrag[3][3], zf[3], acc[3], 0, 0, 0);
        const float dg = pack4p<P>(acc[2]);
        const float eg = __builtin_amdgcn_exp2f(dg);
        const float di = pack4p<P>(acc[0]);
        const float ei = __builtin_amdgcn_exp2f(di);
        const float df = pack4p<P>(acc[1]);
        const float ef = __builtin_amdgcn_exp2f(df);
        const float af  = 1.0f + ef;
        const float t1  = (1.0f + ei) * (1.0f + eg);
        const float num = fmaf(c_st, t1, (1.0f - eg) * af);
        const float den = af * t1;
        const float dojj = pack4p<P>(acc[3]);
        const float eo  = __builtin_amdgcn_exp2f(dojj);
        const float p_o = 1.0f + eo;
        #pragma unroll
        for (int kq = 0; kq < 4; ++kq) {
            __builtin_amdgcn_sched_group_barrier(0x008, 1, 0);  // 1 MFMA
            __builtin_amdgcn_sched_group_barrier(0x002, 6, 0);  // 6 VALU
        }
        __builtin_amdgcn_sched_barrier(0);

        // ---- P3: serial tail covered by next-quad gate-P reseed MFMA ----
        accn[P] = __builtin_amdgcn_mfma_f32_16x16x32_bf16(wfrag[P][4], zx4r, biasC[P], 0, 0, 0);
        const float cn = num * __builtin_amdgcn_rcpf(den);
        c_st = cn;
        const float ec = __builtin_amdgcn_exp2f(fminf(cn * (2.0f * kNL2E), 40.f));
        const float hn = (1.0f - ec) * __builtin_amdgcn_rcpf(p_o * (1.0f + ec));
        h_ep = hn;
        if ((c16 & 2) == 0)                                  // rows nb<2 only
            hw[P * 512 + waddr] = (unsigned short)pk_bf16(hn, hn);
        if constexpr (P == 3) {
            // prefetch zx4 for quad Q+2 (consumed by next quad's reseeds)
            zx4r = *(const s16x8*)(xb + xqoff);
            xqoff = (xqoff + 1024) & 16383;
        }
        __syncthreads();
    };

    auto maint = [&](int Q) {
        const int qi = Q & 7;
        const int chunkI = Q >> 3;
        if (qi < 2) {
            if (chunkI < (T_LEN / CHUNK) - 1) {
                const int flat4 = tid * 4;
                const int b_loc = flat4 >> 9;
                const int rem   = flat4 & 511;
                if (b_loc < NROWS) {
                    const int slot = rem >> 4, f = rem & 15;
                    const int qs = slot >> 2, s = slot & 3;
                    const int nb1 = (chunkI + 1) & 1;
                    const int k0 = f + 2 * qi;
                    unsigned* dst = (unsigned*)&xq[nb1 * 4096 + qs * 512 + (k0 >> 3) * 128 + (4 * s + b_loc) * 8 + (k0 & 7)];
                    dst[0] = pk_bf16(xreg[2 * qi], xreg[2 * qi + 1]);
                }
            }
        } else if (qi == 4) {
            const int tnext = (chunkI + 2) * CHUNK;
            if (tnext < T_LEN) {
                const int flat4 = tid * 4;
                const int b_loc = flat4 >> 9;
                const int rem   = flat4 & 511;
                if (b_loc < NROWS)
                    xreg = *(const f32x4*)(x + (size_t)(b0 + b_loc) * (T_LEN * IN_DIM)
                                             + (size_t)tnext * IN_DIM + rem);
            }
        }
    };

    for (int Q = 0; Q < T_LEN / 4; Q += 2) {
        phaseF(std::integral_constant<int, 0>{}, accA, accB);
        maint(Q);
        phaseF(std::integral_constant<int, 1>{}, accA, accB);
        phaseF(std::integral_constant<int, 2>{}, accA, accB);
        phaseF(std::integral_constant<int, 3>{}, accA, accB);
        phaseF(std::integral_constant<int, 0>{}, accB, accA);
        maint(Q + 1);
        phaseF(std::integral_constant<int, 1>{}, accB, accA);
        phaseF(std::integral_constant<int, 2>{}, accB, accA);
        phaseF(std::integral_constant<int, 3>{}, accB, accA);
    }

    // ---- epilogue: out[b] = sum_cols h * fc_w + fc_b (rows nb<2) ----
    float v = h_ep * fc_w[col];
    v += __shfl_xor(v, 4);
    v += __shfl_xor(v, 8);
    v += __shfl_xor(v, 16);
    v += __shfl_xor(v, 32);
    if (tid < NROWS) red[tid] = 0.0f;
    __syncthreads();
    if (lane < NROWS) atomicAdd(&red[nb], v);
    __syncthreads();
    if (tid < NROWS) out[b0 + tid] = red[tid] + fc_b[0];
}

extern "C" void kernel_launch(void* const* d_in, const int* in_sizes, int n_in,
                              void* d_out, int out_size, void* d_ws, size_t ws_size,
                              hipStream_t stream) {
    const float* x    = (const float*)d_in[0];
    const float* W_ih = (const float*)d_in[1];
    const float* W_hh = (const float*)d_in[2];
    const float* b_ih = (const float*)d_in[3];
    const float* b_hh = (const float*)d_in[4];
    const float* fc_w = (const float*)d_in[5];
    const float* fc_b = (const float*)d_in[6];
    float* out = (float*)d_out;

    slstm_persistent<<<512, 512, 0, stream>>>(x, W_ih, W_hh, b_ih, b_hh, fc_w, fc_b, out);
}

// Round 8
// 1104.385 us; speedup vs baseline: 2.5703x; 2.5703x over previous
//
#include <hip/hip_runtime.h>
#include <hip/hip_bf16.h>
#include <type_traits>

// SLSTM recurrence + Linear.  B=1024, T=2048, IN=16, H=128, OUT=1.
// R18 = R16 (verified 1030us) + full-region SGB interleave:
//   R16 budget: step 1207 cyc/SIMD = matrix 615 (34 MFMA x ~18, N-fill-4
//   h-GEMM floor) + ~290 VALU/trans issue + ~250 serial window (cn-chain
//   ~120 + write/barrier ~50 + post-barrier zf latency ~100).  R12's SGB
//   only covered the 4-MFMA o-chain; packs/exp2/num/den still ran AFTER all
//   16 MFMAs.  R18 pins {10 MFMA}(g done) then {1 MFMA : n VALU} so the
//   whole elementwise front issues under MFMA #11..#17; only ec->hn (~70)
//   + barrier + zf latency stay exposed.  Schedule-only, math identical.
//   (Resubmitted: previous round was an infra failure, kernel unmeasured.)
// R17 lesson (2.8ms disaster): __launch_bounds__(512,4) => hipcc caps VGPR
//   at 64 => full spill to scratch (FETCH 66MB->6GB).  Keep (512,2).  Also
//   NROWS=2 dual-WG is a wash by arithmetic: halving rows/WG doubles
//   per-SIMD MFMA issue (68x18 >= 1207).  Stay 256 WGs x NROWS=4, 1 WG/CU.
// R15/R16: quad-batched x-projection at N-fill 16 (17 MFMA/wave/step);
//   rotating reader window, broadcast-zero for out-of-window lanes (R16
//   conflict fix, 70.8M->20.4M); pack4p<P> dpp extraction; reseed gate P at
//   phase P.  R13/R14: no chain-flattening; cvt_pk h-write; o-gate hoisted.

#define T_LEN 2048
#define IN_DIM 16
#define CHUNK 32
#define NROWS 4

typedef __attribute__((ext_vector_type(4))) float f32x4;
typedef __attribute__((ext_vector_type(8))) short s16x8;

__device__ __forceinline__ short f2bf(float f) {
    union { float f; unsigned u; } v; v.f = f;
    unsigned r = v.u + 0x7fffu + ((v.u >> 16) & 1u);   // RNE
    return (short)(r >> 16);
}
__device__ __forceinline__ unsigned pk_bf16(float a, float b) {
#if __has_builtin(__builtin_amdgcn_cvt_pk_bf16_f32)
    typedef __attribute__((ext_vector_type(2))) __bf16 bf16x2;
    bf16x2 r = __builtin_amdgcn_cvt_pk_bf16_f32(a, b);
    union { bf16x2 v; unsigned u; } c; c.v = r;
    return c.u;
#else
    return (unsigned)(unsigned short)f2bf(a) | ((unsigned)(unsigned short)f2bf(b) << 16);
#endif
}
// Phase-P pack: lane group e (lanes 4e..4e+3 of each 16-row) takes acc reg e
// from source lane 4P+nb via row_ror:4((e-P)&3).  Shift amounts are fixed
// (4,8,12); only the bank masks rotate with P.  P=0 == verified R10 pack4.
template<int P>
__device__ __forceinline__ float pack4p(const f32x4& a) {
    int d = __float_as_int(a[P]);
    d = __builtin_amdgcn_update_dpp(d, __float_as_int(a[(P + 1) & 3]), 0x124, 0xF, 1 << ((P + 1) & 3), false);
    d = __builtin_amdgcn_update_dpp(d, __float_as_int(a[(P + 2) & 3]), 0x128, 0xF, 1 << ((P + 2) & 3), false);
    d = __builtin_amdgcn_update_dpp(d, __float_as_int(a[(P + 3) & 3]), 0x12C, 0xF, 1 << ((P + 3) & 3), false);
    return __int_as_float(d);
}

__global__ __launch_bounds__(512, 2)
void slstm_persistent(const float* __restrict__ x,
                      const float* __restrict__ W_ih,
                      const float* __restrict__ W_hh,
                      const float* __restrict__ b_ih,
                      const float* __restrict__ b_hh,
                      const float* __restrict__ fc_w,
                      const float* __restrict__ fc_b,
                      float* __restrict__ out)
{
    // h: 5 buffers x [kf 4][chunk 16][8 shorts]; element (k=col, nb) at
    // shorts[(k>>5)*128 + ((k>>3)&3)*32 + nb*8 + (k&7)].  Buffer p written at
    // phase p; buffer 4 permanently zero (read broadcast by non-window lanes).
    __shared__ __align__(16) unsigned short h_frag[5][512];
    // x quad-frags: [buf 2][quadslot 8][512 shorts]; B[k][c=4s+nb] chunk
    // layout: 16B chunk index = (k>>3)*16 + c  (reader lane reads lane*16).
    // k>=16 halves permanently zero (IN_DIM=16; also W_ih frag zeros k>=16).
    __shared__ __align__(16) unsigned short xq[8192];     // 16 KB
    __shared__ float red[NROWS];

    const int tid  = threadIdx.x;
    const int lane = tid & 63;
    const int wv   = tid >> 6;          // wave 0..7 = col-group
    const int c16  = lane & 15;
    const int quad = lane >> 4;         // 0..3
    const int b0   = blockIdx.x * NROWS;

    const float kNL2E = -1.44269504f;

    // ---- weights pre-scaled; wave owns col-group wv x 4 gates ----
    s16x8 wfrag[4][5];                  // [g][kf], kf4 = x (k>=IN_DIM zeroed)
    f32x4 biasC[4];
    #pragma unroll
    for (int g = 0; g < 4; ++g) {
        const float scale = (g == 2) ? (2.0f * kNL2E) : kNL2E;
        const int n = g * 128 + wv * 16 + c16;
        #pragma unroll
        for (int kf = 0; kf < 5; ++kf) {
            s16x8 fr;
            #pragma unroll
            for (int j = 0; j < 8; ++j) {
                const int k = kf * 32 + quad * 8 + j;
                float v;
                if (kf < 4) v = W_hh[n * 128 + k];
                else {
                    const int kk = k - 128;
                    v = (kk < IN_DIM) ? W_ih[n * IN_DIM + kk] : 0.0f;
                }
                fr[j] = f2bf(v * scale);
            }
            wfrag[g][kf] = fr;
        }
        #pragma unroll
        for (int r = 0; r < 4; ++r) {
            const int m = g * 128 + wv * 16 + quad * 4 + r;
            biasC[g][r] = (b_ih[m] + b_hh[m]) * scale;
        }
    }

    // ---- zero h buffers (incl. zero-source buf 4) and xq (k>=16 holes) ----
    {
        unsigned* hz = (unsigned*)h_frag;      // 1280 unsigneds (5120 B)
        hz[tid] = 0; hz[tid + 512] = 0;
        if (tid < 256) hz[tid + 1024] = 0;
        unsigned* xz = (unsigned*)xq;          // 4096 unsigneds (16 KB)
        #pragma unroll
        for (int i = 0; i < 8; ++i) xz[tid + i * 512] = 0;
    }
    __syncthreads();

    // ---- packed-lane identity: element (col, nb) — fixed across phases ----
    const int e    = c16 >> 2;
    const int nb   = c16 & 3;
    const int col  = wv * 16 + quad * 4 + e;
    const int waddr = (col >> 5) * 128 + ((col >> 3) & 3) * 32 + nb * 8 + (col & 7);
    // per-phase h read offset: window lanes (c16>>2 == p) read buffer (p+3)&3
    // at chunk quad*4 + (c16&3); all other lanes read ONE broadcast address
    // (zero buf 4, offset 0) -> no conflicts (R16 fix).
    int hoffP[4];
    #pragma unroll
    for (int q = 0; q < 4; ++q)
        hoffP[q] = ((c16 >> 2) == q)
                 ? ((q + 3) & 3) * 1024 + (quad * 4 + (c16 & 3)) * 16
                 : 4 * 1024;

    float c_st = 0.0f, h_ep = 0.0f;

    // ---- prologue: stage chunk 0 -> xq buf0 (quad layout); chunk1 -> xreg ----
    f32x4 xreg;
    {
        const int flat4 = tid * 4;
        const int b_loc = flat4 >> 9;
        const int rem   = flat4 & 511;
        const float* xr = x + (size_t)(b0 + b_loc) * (T_LEN * IN_DIM);
        f32x4 v4 = *(const f32x4*)(xr + rem);
        const int slot = rem >> 4, f = rem & 15;      // ts-in-chunk, feat base
        const int qs = slot >> 2, s = slot & 3;
        unsigned* dst = (unsigned*)&xq[qs * 512 + (f >> 3) * 128 + (4 * s + b_loc) * 8 + (f & 7)];
        dst[0] = pk_bf16(v4[0], v4[1]);
        dst[1] = pk_bf16(v4[2], v4[3]);
        xreg = *(const f32x4*)(xr + CHUNK * IN_DIM + rem);
    }
    __syncthreads();

    // ---- seed quad 0: zx4 walks 1 KB per quad through the 16 KB xq ----
    const char* xb = (const char*)xq;
    s16x8 zx4r = *(const s16x8*)(xb + lane * 16);           // quad 0
    f32x4 accA[4], accB[4];
    #pragma unroll
    for (int g = 0; g < 4; ++g)
        accA[g] = __builtin_amdgcn_mfma_f32_16x16x32_bf16(wfrag[g][4], zx4r, biasC[g], 0, 0, 0);
    zx4r = *(const s16x8*)(xb + 1024 + lane * 16);          // quad 1
    int xqoff = 2 * 1024 + lane * 16;                       // next prefetch: quad 2

    const char* hb = (const char*)h_frag;
    unsigned short* hw = (unsigned short*)h_frag;

    // one phase = one timestep.  acc: current quad's gates; accn: next quad's
    // seeds (gate P reseeded at phase P).
    auto phaseF = [&](auto Pc, f32x4 (&acc)[4], f32x4 (&accn)[4]) {
        constexpr int P = decltype(Pc)::value;
        s16x8 zf[4];
        #pragma unroll
        for (int kf = 0; kf < 4; ++kf)
            zf[kf] = *(const s16x8*)(hb + hoffP[P] + kf * 256);

        // MFMA program order: g,i,f interleaved over kf (g completes at #10,
        // i at #11, f at #12), o-chain #13-16, reseed #17.  The SGB block
        // below threads the elementwise front between #10..#17 so it issues
        // on the VALU pipe while the matrix pipe drains.
        acc[2] = __builtin_amdgcn_mfma_f32_16x16x32_bf16(wfrag[2][0], zf[0], acc[2], 0, 0, 0); // 1
        acc[0] = __builtin_amdgcn_mfma_f32_16x16x32_bf16(wfrag[0][0], zf[0], acc[0], 0, 0, 0); // 2
        acc[1] = __builtin_amdgcn_mfma_f32_16x16x32_bf16(wfrag[1][0], zf[0], acc[1], 0, 0, 0); // 3
        acc[2] = __builtin_amdgcn_mfma_f32_16x16x32_bf16(wfrag[2][1], zf[1], acc[2], 0, 0, 0); // 4
        acc[0] = __builtin_amdgcn_mfma_f32_16x16x32_bf16(wfrag[0][1], zf[1], acc[0], 0, 0, 0); // 5
        acc[1] = __builtin_amdgcn_mfma_f32_16x16x32_bf16(wfrag[1][1], zf[1], acc[1], 0, 0, 0); // 6
        acc[2] = __builtin_amdgcn_mfma_f32_16x16x32_bf16(wfrag[2][2], zf[2], acc[2], 0, 0, 0); // 7
        acc[0] = __builtin_amdgcn_mfma_f32_16x16x32_bf16(wfrag[0][2], zf[2], acc[0], 0, 0, 0); // 8
        acc[1] = __builtin_amdgcn_mfma_f32_16x16x32_bf16(wfrag[1][2], zf[2], acc[1], 0, 0, 0); // 9
        acc[2] = __builtin_amdgcn_mfma_f32_16x16x32_bf16(wfrag[2][3], zf[3], acc[2], 0, 0, 0); // 10 g done
        acc[0] = __builtin_amdgcn_mfma_f32_16x16x32_bf16(wfrag[0][3], zf[3], acc[0], 0, 0, 0); // 11 i done
        acc[1] = __builtin_amdgcn_mfma_f32_16x16x32_bf16(wfrag[1][3], zf[3], acc[1], 0, 0, 0); // 12 f done
        acc[3] = __builtin_amdgcn_mfma_f32_16x16x32_bf16(wfrag[3][0], zf[0], acc[3], 0, 0, 0); // 13
        acc[3] = __builtin_amdgcn_mfma_f32_16x16x32_bf16(wfrag[3][1], zf[1], acc[3], 0, 0, 0); // 14
        acc[3] = __builtin_amdgcn_mfma_f32_16x16x32_bf16(wfrag[3][2], zf[2], acc[3], 0, 0, 0); // 15
        acc[3] = __builtin_amdgcn_mfma_f32_16x16x32_bf16(wfrag[3][3], zf[3], acc[3], 0, 0, 0); // 16 o done
        accn[P] = __builtin_amdgcn_mfma_f32_16x16x32_bf16(wfrag[P][4], zx4r, biasC[P], 0, 0, 0); // 17 reseed

        // elementwise front + serial tail (program order = dependency order;
        // SGB interleaves it under MFMAs #11..#17)
        const float dg = pack4p<P>(acc[2]);
        const float eg = __builtin_amdgcn_exp2f(dg);
        const float di = pack4p<P>(acc[0]);
        const float ei = __builtin_amdgcn_exp2f(di);
        const float df = pack4p<P>(acc[1]);
        const float ef = __builtin_amdgcn_exp2f(df);
        const float af  = 1.0f + ef;
        const float t1  = (1.0f + ei) * (1.0f + eg);
        const float num = fmaf(c_st, t1, (1.0f - eg) * af);
        const float den = af * t1;
        const float cn = num * __builtin_amdgcn_rcpf(den);
        c_st = cn;
        const float dojj = pack4p<P>(acc[3]);
        const float eo  = __builtin_amdgcn_exp2f(dojj);
        const float p_o = 1.0f + eo;
        const float ec = __builtin_amdgcn_exp2f(fminf(cn * (2.0f * kNL2E), 40.f));
        const float hn = (1.0f - ec) * __builtin_amdgcn_rcpf(p_o * (1.0f + ec));
        h_ep = hn;
        hw[P * 512 + waddr] = (unsigned short)pk_bf16(hn, hn);

        // ---- SGB pin: {10 MFMA} then 1:N MFMA/VALU interleave ----
        __builtin_amdgcn_sched_group_barrier(0x008, 10, 0);  // #1-10 (g done)
        __builtin_amdgcn_sched_group_barrier(0x002, 4, 0);   // pack g (3 dpp) + exp2 dg
        __builtin_amdgcn_sched_group_barrier(0x008, 1, 0);   // #11 (i done)
        __builtin_amdgcn_sched_group_barrier(0x002, 4, 0);   // pack i + exp2 di
        __builtin_amdgcn_sched_group_barrier(0x008, 1, 0);   // #12 (f done)
        __builtin_amdgcn_sched_group_barrier(0x002, 4, 0);   // pack f + exp2 df
        __builtin_amdgcn_sched_group_barrier(0x008, 1, 0);   // #13 o-chain
        __builtin_amdgcn_sched_group_barrier(0x002, 6, 0);   // af,1+ei,1+eg,t1,1-eg,(1-eg)af
        __builtin_amdgcn_sched_group_barrier(0x008, 1, 0);   // #14
        __builtin_amdgcn_sched_group_barrier(0x002, 3, 0);   // num, den, rcp(den)
        __builtin_amdgcn_sched_group_barrier(0x008, 1, 0);   // #15
        __builtin_amdgcn_sched_group_barrier(0x002, 2, 0);   // cn, cn*2k
        __builtin_amdgcn_sched_group_barrier(0x008, 1, 0);   // #16 (o done)
        __builtin_amdgcn_sched_group_barrier(0x002, 5, 0);   // pack o (3 dpp) + exp2 eo + p_o
        __builtin_amdgcn_sched_group_barrier(0x008, 1, 0);   // #17 reseed covers ec->hn
        __builtin_amdgcn_sched_barrier(0);

        if constexpr (P == 3) {
            // prefetch zx4 for quad Q+2 (consumed by next quad's reseeds)
            zx4r = *(const s16x8*)(xb + xqoff);
            xqoff = (xqoff + 1024) & 16383;
        }
        __syncthreads();
    };

    auto maint = [&](int Q) {
        const int qi = Q & 7;
        const int chunkI = Q >> 3;
        if (qi < 2) {
            if (chunkI < (T_LEN / CHUNK) - 1) {
                const int flat4 = tid * 4;
                const int b_loc = flat4 >> 9;
                const int rem   = flat4 & 511;
                const int slot = rem >> 4, f = rem & 15;
                const int qs = slot >> 2, s = slot & 3;
                const int nb1 = (chunkI + 1) & 1;
                const int k0 = f + 2 * qi;
                unsigned* dst = (unsigned*)&xq[nb1 * 4096 + qs * 512 + (k0 >> 3) * 128 + (4 * s + b_loc) * 8 + (k0 & 7)];
                dst[0] = pk_bf16(xreg[2 * qi], xreg[2 * qi + 1]);
            }
        } else if (qi == 4) {
            const int tnext = (chunkI + 2) * CHUNK;
            if (tnext < T_LEN) {
                const int flat4 = tid * 4;
                const int b_loc = flat4 >> 9;
                const int rem   = flat4 & 511;
                xreg = *(const f32x4*)(x + (size_t)(b0 + b_loc) * (T_LEN * IN_DIM)
                                         + (size_t)tnext * IN_DIM + rem);
            }
        }
    };

    for (int Q = 0; Q < T_LEN / 4; Q += 2) {
        phaseF(std::integral_constant<int, 0>{}, accA, accB);
        maint(Q);
        phaseF(std::integral_constant<int, 1>{}, accA, accB);
        phaseF(std::integral_constant<int, 2>{}, accA, accB);
        phaseF(std::integral_constant<int, 3>{}, accA, accB);
        phaseF(std::integral_constant<int, 0>{}, accB, accA);
        maint(Q + 1);
        phaseF(std::integral_constant<int, 1>{}, accB, accA);
        phaseF(std::integral_constant<int, 2>{}, accB, accA);
        phaseF(std::integral_constant<int, 3>{}, accB, accA);
    }

    // ---- epilogue: out[b] = sum_cols h * fc_w + fc_b ----
    float v = h_ep * fc_w[col];
    v += __shfl_xor(v, 4);
    v += __shfl_xor(v, 8);
    v += __shfl_xor(v, 16);
    v += __shfl_xor(v, 32);
    if (tid < NROWS) red[tid] = 0.0f;
    __syncthreads();
    if (lane < NROWS) atomicAdd(&red[nb], v);
    __syncthreads();
    if (tid < NROWS) out[b0 + tid] = red[tid] + fc_b[0];
}

extern "C" void kernel_launch(void* const* d_in, const int* in_sizes, int n_in,
                              void* d_out, int out_size, void* d_ws, size_t ws_size,
                              hipStream_t stream) {
    const float* x    = (const float*)d_in[0];
    const float* W_ih = (const float*)d_in[1];
    const float* W_hh = (const float*)d_in[2];
    const float* b_ih = (const float*)d_in[3];
    const float* b_hh = (const float*)d_in[4];
    const float* fc_w = (const float*)d_in[5];
    const float* fc_b = (const float*)d_in[6];
    float* out = (float*)d_out;

    slstm_persistent<<<256, 512, 0, stream>>>(x, W_ih, W_hh, b_ih, b_hh, fc_w, fc_b, out);
}